// Round 1
// baseline (417.996 us; speedup 1.0000x reference)
//
#include <hip/hip_runtime.h>
#include <math.h>

#define N_NODES 100000
#define N_EDGES 1000000
#define IN_DIM 64
#define OUT_DIM 64
#define N_REL 4
#define KTOT 320   // 256 (acc: 4 rel x 64) + 64 (x for root term)

// ---------------------------------------------------------------------------
// Phase 1: edge scatter. One wave (64 lanes) per edge; lane = feature index.
// acc[dst][rel][feat] += x[src][feat];  cnt[dst] += 1
// ---------------------------------------------------------------------------
__global__ __launch_bounds__(256) void edge_scatter(
    const int* __restrict__ ei, const int* __restrict__ et,
    const float* __restrict__ x, float* __restrict__ acc,
    float* __restrict__ cnt)
{
    int wave = (blockIdx.x * blockDim.x + threadIdx.x) >> 6;
    int lane = threadIdx.x & 63;
    if (wave >= N_EDGES) return;
    int src = ei[wave];
    int dst = ei[N_EDGES + wave];
    int rel = et[wave];
    float v = x[(size_t)src * IN_DIM + lane];
    atomicAdd(&acc[((size_t)dst * N_REL + rel) * IN_DIM + lane], v);
    if (lane == 0) atomicAdd(&cnt[dst], 1.0f);
}

// ---------------------------------------------------------------------------
// Phase 2: fused GEMM + mean + root + bias + tanh.
// out[n][o] = tanh( sum_{k<256} (acc[n][k]*inv[n]) * W[k][o]
//                 + sum_{k<64}  x[n][k] * root[k][o] + bias[o] )
// Tiled: 64 nodes x 64 outs per block (256 thr), 4x4 micro-tile, BK=32.
// ---------------------------------------------------------------------------
__global__ __launch_bounds__(256) void fused_out(
    const float* __restrict__ acc, const float* __restrict__ cnt,
    const float* __restrict__ x, const float* __restrict__ weight,
    const float* __restrict__ root, const float* __restrict__ bias,
    float* __restrict__ out)
{
    __shared__ float As[64][33];   // [node][kk], +1 pad: conflict-free col reads
    __shared__ float Bs[32][64];   // [kk][o]
    __shared__ float invs[64];

    int tid = threadIdx.x;
    int nb = blockIdx.x * 64;

    if (tid < 64) {
        int ng = nb + tid;
        float c = (ng < N_NODES) ? cnt[ng] : 1.0f;
        invs[tid] = 1.0f / fmaxf(c, 1.0f);
    }
    __syncthreads();

    int tx = tid & 15;     // output group (o = tx*4 .. tx*4+3)
    int ty = tid >> 4;     // node group  (n = ty*4 .. ty*4+3)
    float c[4][4] = {};

    for (int ko = 0; ko < KTOT; ko += 32) {
        __syncthreads();
        // stage A: 64 nodes x 32 k (coalesced: consecutive tid -> consecutive k)
        #pragma unroll
        for (int it = 0; it < 8; ++it) {
            int idx = it * 256 + tid;
            int n = idx >> 5, kk = idx & 31;
            int k = ko + kk, ng = nb + n;
            float v = 0.f;
            if (ng < N_NODES) {
                if (k < 256) v = acc[(size_t)ng * 256 + k] * invs[n];
                else         v = x[(size_t)ng * IN_DIM + (k - 256)];
            }
            As[n][kk] = v;
        }
        // stage B: 32 k x 64 o (coalesced along o)
        #pragma unroll
        for (int it = 0; it < 8; ++it) {
            int idx = it * 256 + tid;
            int kk = idx >> 6, o = idx & 63;
            int k = ko + kk;
            Bs[kk][o] = (k < 256) ? weight[k * 64 + o]
                                  : root[(k - 256) * 64 + o];
        }
        __syncthreads();
        #pragma unroll
        for (int kk = 0; kk < 32; ++kk) {
            float b0 = Bs[kk][tx * 4 + 0];
            float b1 = Bs[kk][tx * 4 + 1];
            float b2 = Bs[kk][tx * 4 + 2];
            float b3 = Bs[kk][tx * 4 + 3];
            #pragma unroll
            for (int j = 0; j < 4; ++j) {
                float a = As[ty * 4 + j][kk];
                c[j][0] += a * b0;
                c[j][1] += a * b1;
                c[j][2] += a * b2;
                c[j][3] += a * b3;
            }
        }
    }

    float bo[4];
    #pragma unroll
    for (int l = 0; l < 4; ++l) bo[l] = bias[tx * 4 + l];
    #pragma unroll
    for (int j = 0; j < 4; ++j) {
        int ng = nb + ty * 4 + j;
        if (ng < N_NODES) {
            #pragma unroll
            for (int l = 0; l < 4; ++l)
                out[(size_t)ng * OUT_DIM + tx * 4 + l] = tanhf(c[j][l] + bo[l]);
        }
    }
}

extern "C" void kernel_launch(void* const* d_in, const int* in_sizes, int n_in,
                              void* d_out, int out_size, void* d_ws, size_t ws_size,
                              hipStream_t stream) {
    const float* x      = (const float*)d_in[0];
    const int*   ei     = (const int*)d_in[1];   // [2, E] (harness: int64 -> int32)
    const int*   et     = (const int*)d_in[2];   // [E]
    const float* weight = (const float*)d_in[3]; // [4,64,64]
    const float* root   = (const float*)d_in[4]; // [64,64]
    const float* bias   = (const float*)d_in[5]; // [64]
    float* out = (float*)d_out;

    float* acc = (float*)d_ws;                        // N * 256 floats (102.4 MB)
    float* cnt = acc + (size_t)N_NODES * 256;         // N floats
    size_t zero_bytes = ((size_t)N_NODES * 256 + N_NODES) * sizeof(float);
    hipMemsetAsync(d_ws, 0, zero_bytes, stream);

    dim3 blk(256);
    edge_scatter<<<dim3((N_EDGES + 3) / 4), blk, 0, stream>>>(ei, et, x, acc, cnt);
    fused_out<<<dim3((N_NODES + 63) / 64), blk, 0, stream>>>(acc, cnt, x, weight,
                                                             root, bias, out);
}